// Round 1
// baseline (741.890 us; speedup 1.0000x reference)
//
#include <hip/hip_runtime.h>
#include <hip/hip_bf16.h>
#include <stdint.h>

typedef __attribute__((ext_vector_type(8))) short short8;
typedef __attribute__((ext_vector_type(4))) float f32x4;
typedef __attribute__((ext_vector_type(4))) unsigned short ushort4v;
typedef __attribute__((ext_vector_type(8))) unsigned short ushort8v;

__device__ __forceinline__ unsigned short f2bf(float f) {
  union { float f; uint32_t u; } v; v.f = f;
  uint32_t u = v.u;
  u += 0x7fffu + ((u >> 16) & 1u);   // round-to-nearest-even
  return (unsigned short)(u >> 16);
}

// ---------------------------------------------------------------------------
// Generic C = A * B^T GEMM.  A: [M,K] (fp32 or bf16) row-major, B: [N,K] bf16
// row-major.  BM=BN=128, BK=32, 256 threads = 4 waves, each wave does a 64x64
// quadrant as 4x4 grid of 16x16x32 bf16 MFMAs.
// EPI 0: C[bf16] = val + bias[col] ;  EPI 1: C[f32] = val * scale
// ---------------------------------------------------------------------------
#define BM 128
#define BN 128
#define BK 32
#define LDSK 40   // BK + 8 pad (elements)

template<bool A_FP32, int EPI>
__global__ __launch_bounds__(256) void gemm_kernel(
    const void* __restrict__ Abase, const unsigned short* __restrict__ Bbase,
    void* __restrict__ Cbase, const float* __restrict__ bias, float scale,
    int lda, int ldb, int ldc, int K,
    long long sA, long long sB, long long sC)
{
  __shared__ __align__(16) unsigned short As[BM * LDSK];
  __shared__ __align__(16) unsigned short Bs[BN * LDSK];

  const int tid  = threadIdx.x;
  const int z    = blockIdx.z;
  const int m0   = blockIdx.x * BM;
  const int n0   = blockIdx.y * BN;
  const int wave = tid >> 6;
  const int lane = tid & 63;
  const int l16  = lane & 15;
  const int quad = lane >> 4;
  const int wm   = (wave >> 1) * 64;
  const int wn   = (wave & 1) * 64;

  const unsigned short* B = Bbase + (size_t)z * (size_t)sB;

  f32x4 acc[4][4] = {};

  const int nk = K / BK;
  for (int kt = 0; kt < nk; ++kt) {
    const int k0 = kt * BK;
    // ---- stage A tile (128 x 32) ----
    if (A_FP32) {
      const float* A = (const float*)Abase + (size_t)z * (size_t)sA;
      #pragma unroll
      for (int i = 0; i < 4; ++i) {
        int f  = tid + i * 256;         // float4 index, 1024 total (8 per row)
        int r  = f >> 3;
        int kk = (f & 7) * 4;
        const float4 t = *(const float4*)(A + (size_t)(m0 + r) * lda + k0 + kk);
        ushort4v h;
        h.x = f2bf(t.x); h.y = f2bf(t.y); h.z = f2bf(t.z); h.w = f2bf(t.w);
        *(ushort4v*)&As[r * LDSK + kk] = h;
      }
    } else {
      const unsigned short* A = (const unsigned short*)Abase + (size_t)z * (size_t)sA;
      #pragma unroll
      for (int i = 0; i < 2; ++i) {
        int c  = tid + i * 256;         // 8-elem chunk index, 512 total (4/row)
        int r  = c >> 2;
        int kk = (c & 3) * 8;
        ushort8v t = *(const ushort8v*)(A + (size_t)(m0 + r) * lda + k0 + kk);
        *(ushort8v*)&As[r * LDSK + kk] = t;
      }
    }
    // ---- stage B tile (128 x 32), B is [N][K] bf16 row-major ----
    #pragma unroll
    for (int i = 0; i < 2; ++i) {
      int c  = tid + i * 256;
      int r  = c >> 2;
      int kk = (c & 3) * 8;
      ushort8v t = *(const ushort8v*)(B + (size_t)(n0 + r) * ldb + k0 + kk);
      *(ushort8v*)&Bs[r * LDSK + kk] = t;
    }
    __syncthreads();

    // ---- compute: fragments straight off LDS (ds_read_b128) ----
    short8 af[4], bfr[4];
    #pragma unroll
    for (int mt = 0; mt < 4; ++mt)
      af[mt] = *(const short8*)&As[(wm + mt * 16 + l16) * LDSK + quad * 8];
    #pragma unroll
    for (int nt = 0; nt < 4; ++nt)
      bfr[nt] = *(const short8*)&Bs[(wn + nt * 16 + l16) * LDSK + quad * 8];
    #pragma unroll
    for (int mt = 0; mt < 4; ++mt)
      #pragma unroll
      for (int nt = 0; nt < 4; ++nt)
        acc[mt][nt] = __builtin_amdgcn_mfma_f32_16x16x32_bf16(
            af[mt], bfr[nt], acc[mt][nt], 0, 0, 0);
    __syncthreads();
  }

  // ---- epilogue.  D layout: col = lane&15, row = quad*4 + reg ----
  #pragma unroll
  for (int mt = 0; mt < 4; ++mt) {
    #pragma unroll
    for (int nt = 0; nt < 4; ++nt) {
      #pragma unroll
      for (int r = 0; r < 4; ++r) {
        int Rg = m0 + wm + mt * 16 + quad * 4 + r;
        int Cg = n0 + wn + nt * 16 + l16;
        float val = acc[mt][nt][r];
        if (EPI == 0) {
          val += bias[Cg];
          ((unsigned short*)Cbase)[(size_t)z * (size_t)sC + (size_t)Rg * ldc + Cg] = f2bf(val);
        } else {
          ((float*)Cbase)[(size_t)z * (size_t)sC + (size_t)Rg * ldc + Cg] = val * scale;
        }
      }
    }
  }
}

// ---------------------------------------------------------------------------
// Wq [1024x1024] fp32 -> Wt [1024x1024] bf16 transposed (Wt[n][k] = Wq[k][n])
// ---------------------------------------------------------------------------
__global__ __launch_bounds__(256) void transpose_w(
    const float* __restrict__ W, unsigned short* __restrict__ Wt)
{
  __shared__ float tile[64][65];
  const int k0 = blockIdx.x * 64;
  const int n0 = blockIdx.y * 64;
  #pragma unroll
  for (int i = 0; i < 16; ++i) {
    int lin = threadIdx.x + i * 256;
    int r = lin >> 6, c = lin & 63;
    tile[r][c] = W[(size_t)(k0 + r) * 1024 + n0 + c];
  }
  __syncthreads();
  #pragma unroll
  for (int i = 0; i < 16; ++i) {
    int lin = threadIdx.x + i * 256;
    int r = lin >> 6, c = lin & 63;
    Wt[(size_t)(n0 + r) * 1024 + k0 + c] = f2bf(tile[c][r]);
  }
}

// ---------------------------------------------------------------------------
// v [b][2048][1024] bf16 -> vT [b][1024][2048] bf16
// ---------------------------------------------------------------------------
__global__ __launch_bounds__(256) void transpose_v(
    const unsigned short* __restrict__ V, unsigned short* __restrict__ VT)
{
  __shared__ unsigned short tile[64][66];   // 66: stride*2B = 132B = 33 banks
  const int b  = blockIdx.z;
  const int s0 = blockIdx.x * 64;
  const int d0 = blockIdx.y * 64;
  const unsigned short* Vb  = V  + (size_t)b * 2048 * 1024;
  unsigned short*       VTb = VT + (size_t)b * 1024 * 2048;
  #pragma unroll
  for (int i = 0; i < 16; ++i) {
    int lin = threadIdx.x + i * 256;
    int r = lin >> 6, c = lin & 63;
    tile[r][c] = Vb[(size_t)(s0 + r) * 1024 + d0 + c];
  }
  __syncthreads();
  #pragma unroll
  for (int i = 0; i < 16; ++i) {
    int lin = threadIdx.x + i * 256;
    int r = lin >> 6, c = lin & 63;
    VTb[(size_t)(d0 + r) * 2048 + s0 + c] = tile[c][r];
  }
}

// ---------------------------------------------------------------------------
// In-place row softmax over 2048-wide fp32 rows (one block per row).
// ---------------------------------------------------------------------------
__global__ __launch_bounds__(256) void softmax_rows(float* __restrict__ L)
{
  const int row  = blockIdx.x;
  float* p = L + (size_t)row * 2048;
  const int tid  = threadIdx.x;
  const int lane = tid & 63;
  const int wave = tid >> 6;

  float4 v0 = ((float4*)p)[tid];
  float4 v1 = ((float4*)p)[tid + 256];

  float mx = fmaxf(fmaxf(fmaxf(v0.x, v0.y), fmaxf(v0.z, v0.w)),
                   fmaxf(fmaxf(v1.x, v1.y), fmaxf(v1.z, v1.w)));
  #pragma unroll
  for (int o = 32; o > 0; o >>= 1) mx = fmaxf(mx, __shfl_xor(mx, o));
  __shared__ float redm[4];
  if (lane == 0) redm[wave] = mx;
  __syncthreads();
  mx = fmaxf(fmaxf(redm[0], redm[1]), fmaxf(redm[2], redm[3]));

  v0.x = __expf(v0.x - mx); v0.y = __expf(v0.y - mx);
  v0.z = __expf(v0.z - mx); v0.w = __expf(v0.w - mx);
  v1.x = __expf(v1.x - mx); v1.y = __expf(v1.y - mx);
  v1.z = __expf(v1.z - mx); v1.w = __expf(v1.w - mx);
  float s = v0.x + v0.y + v0.z + v0.w + v1.x + v1.y + v1.z + v1.w;
  #pragma unroll
  for (int o = 32; o > 0; o >>= 1) s += __shfl_xor(s, o);
  __shared__ float reds[4];
  if (lane == 0) reds[wave] = s;
  __syncthreads();
  s = reds[0] + reds[1] + reds[2] + reds[3];

  const float inv = 1.0f / s;
  v0.x *= inv; v0.y *= inv; v0.z *= inv; v0.w *= inv;
  v1.x *= inv; v1.y *= inv; v1.z *= inv; v1.w *= inv;
  ((float4*)p)[tid]       = v0;
  ((float4*)p)[tid + 256] = v1;
}

// ---------------------------------------------------------------------------
extern "C" void kernel_launch(void* const* d_in, const int* in_sizes, int n_in,
                              void* d_out, int out_size, void* d_ws, size_t ws_size,
                              hipStream_t stream)
{
  const float* query = (const float*)d_in[0];
  const float* key   = (const float*)d_in[1];
  const float* value = (const float*)d_in[2];
  const float* Wq    = (const float*)d_in[3];
  const float* bq    = (const float*)d_in[4];
  float* out = (float*)d_out;

  // workspace layout (bytes):
  //   Wt     [0,   2MB)   bf16 1024x1024 (W transposed)
  //   q      [2,  34MB)   bf16 16384x1024
  //   k      [34, 66MB)   bf16 16384x1024
  //   vT     [66, 98MB)   bf16 8x1024x2048
  //   v      [98, 130MB)  bf16 16384x1024   (dead after transpose_v)
  //   logits [98, 226MB)  f32  8x2048x2048  (overlaps dead v)
  char* ws = (char*)d_ws;
  unsigned short* Wt = (unsigned short*)(ws);
  unsigned short* q  = (unsigned short*)(ws + ((size_t)2  << 20));
  unsigned short* k  = (unsigned short*)(ws + ((size_t)34 << 20));
  unsigned short* vT = (unsigned short*)(ws + ((size_t)66 << 20));
  unsigned short* v  = (unsigned short*)(ws + ((size_t)98 << 20));
  float*          lg = (float*)(ws + ((size_t)98 << 20));

  // 1. W transpose + bf16
  transpose_w<<<dim3(16, 16, 1), 256, 0, stream>>>(Wq, Wt);

  // 2. projections: C[bf16] = X @ Wt^T + bq   (M=16384, N=1024, K=1024)
  dim3 gproj(16384 / BM, 1024 / BN, 1);
  gemm_kernel<true, 0><<<gproj, 256, 0, stream>>>(
      query, Wt, q, bq, 1.0f, 1024, 1024, 1024, 1024, 0, 0, 0);
  gemm_kernel<true, 0><<<gproj, 256, 0, stream>>>(
      key,   Wt, k, bq, 1.0f, 1024, 1024, 1024, 1024, 0, 0, 0);
  gemm_kernel<true, 0><<<gproj, 256, 0, stream>>>(
      value, Wt, v, bq, 1.0f, 1024, 1024, 1024, 1024, 0, 0, 0);

  // 3. v -> vT
  transpose_v<<<dim3(32, 16, 8), 256, 0, stream>>>(v, vT);

  // 4. logits[f32] = (q @ k^T) / 32  per batch (M=2048, N=2048, K=1024)
  gemm_kernel<false, 1><<<dim3(2048 / BM, 2048 / BN, 8), 256, 0, stream>>>(
      q, k, lg, nullptr, 0.03125f, 1024, 1024, 2048, 1024,
      (long long)2048 * 1024, (long long)2048 * 1024, (long long)2048 * 2048);

  // 5. softmax rows, in place
  softmax_rows<<<dim3(8 * 2048, 1, 1), 256, 0, stream>>>(lg);

  // 6. out[f32] = P @ vT^T  per batch (M=2048, N=1024, K=2048)
  gemm_kernel<true, 1><<<dim3(2048 / BM, 1024 / BN, 8), 256, 0, stream>>>(
      lg, vT, out, nullptr, 1.0f, 2048, 2048, 1024, 2048,
      (long long)2048 * 2048, (long long)1024 * 2048, (long long)2048 * 1024);
}

// Round 2
// 620.251 us; speedup vs baseline: 1.1961x; 1.1961x over previous
//
#include <hip/hip_runtime.h>
#include <hip/hip_bf16.h>
#include <stdint.h>

typedef __attribute__((ext_vector_type(8))) short short8;
typedef __attribute__((ext_vector_type(4))) float f32x4;
typedef __attribute__((ext_vector_type(8))) unsigned short ushort8v;

__device__ __forceinline__ unsigned short f2bf(float f) {
  union { float f; uint32_t u; } v; v.f = f;
  uint32_t u = v.u;
  u += 0x7fffu + ((u >> 16) & 1u);   // round-to-nearest-even
  return (unsigned short)(u >> 16);
}
__device__ __forceinline__ unsigned short f2h(float f) {
  union { _Float16 h; unsigned short u; } v; v.h = (_Float16)f; return v.u;
}
__device__ __forceinline__ float h2f(unsigned short u) {
  union { _Float16 h; unsigned short u; } v; v.u = u; return (float)v.h;
}

typedef const __attribute__((address_space(1))) unsigned int* gas_ptr;
typedef __attribute__((address_space(3))) unsigned int* las_ptr;

// DMA 16B per lane: LDS dst = wave-uniform base + lane*16 (hardware rule)
__device__ __forceinline__ void async16(const unsigned short* g, unsigned short* l) {
  __builtin_amdgcn_global_load_lds((gas_ptr)g, (las_ptr)l, 16, 0, 0);
}

// ---------------------------------------------------------------------------
// C = A * B^T, all-bf16 operands.  A:[M,K] bf16 row-major, B:[N,K] bf16
// row-major.  BM=BN=128, BK=32, 256 threads = 4 waves, wave = 64x64 quadrant
// as 4x4 grid of 16x16x32 bf16 MFMAs.  Staging via global_load_lds (16B),
// LDS chunk-swizzled: 16B chunk j of row r stored at slot j ^ ((r>>1)&3)
// so fragment reads land 2-way on banks (free).
// EPI 0: bf16 = val + bias[col]; EPI 1: fp16 = val*scale; EPI 2: f32 = val*scale
// ---------------------------------------------------------------------------
#define BM 128
#define BN 128
#define BK 32

template<int EPI>
__global__ __launch_bounds__(256) void gemm_bf16(
    const unsigned short* __restrict__ Abase,
    const unsigned short* __restrict__ Bbase,
    void* __restrict__ Cbase, const float* __restrict__ bias, float scale,
    int lda, int ldb, int ldc, int K,
    long long sA, long long sB, long long sC)
{
  __shared__ __align__(16) unsigned short As[BM * BK];  // 8 KB
  __shared__ __align__(16) unsigned short Bs[BN * BK];  // 8 KB

  const int tid  = threadIdx.x;
  const int z    = blockIdx.z;
  const int m0   = blockIdx.x * BM;
  const int n0   = blockIdx.y * BN;
  const int wave = tid >> 6;
  const int lane = tid & 63;
  const int l16  = lane & 15;
  const int quad = lane >> 4;
  const int wm   = (wave >> 1) * 64;
  const int wn   = (wave & 1) * 64;

  const unsigned short* A = Abase + (size_t)z * (size_t)sA;
  const unsigned short* B = Bbase + (size_t)z * (size_t)sB;

  f32x4 acc[4][4] = {};

  const int nk = K / BK;
  for (int kt = 0; kt < nk; ++kt) {
    const int k0 = kt * BK;
    // ---- DMA stage A and B tiles (each 128x32 bf16 = 8 KB) ----
    #pragma unroll
    for (int j = 0; j < 2; ++j) {
      const int i  = j * 256 + tid;       // linear 16B-chunk index [0,512)
      const int r  = i >> 2;              // row in tile
      const int s  = i & 3;               // LDS slot within row
      const int jc = s ^ ((r >> 1) & 3);  // global chunk to fetch
      unsigned short* ldst_a = As + (size_t)(j * 256 + wave * 64) * 8; // wave-uniform
      unsigned short* ldst_b = Bs + (size_t)(j * 256 + wave * 64) * 8;
      async16(A + (size_t)(m0 + r) * lda + k0 + jc * 8, ldst_a);
      async16(B + (size_t)(n0 + r) * ldb + k0 + jc * 8, ldst_b);
    }
    __syncthreads();

    // ---- fragments off LDS (ds_read_b128, swizzle-corrected) ----
    short8 af[4], bfr[4];
    #pragma unroll
    for (int mt = 0; mt < 4; ++mt) {
      const int R = wm + mt * 16 + l16;
      const int slot = quad ^ ((R >> 1) & 3);
      af[mt] = *(const short8*)&As[R * BK + slot * 8];
    }
    #pragma unroll
    for (int nt = 0; nt < 4; ++nt) {
      const int R = wn + nt * 16 + l16;
      const int slot = quad ^ ((R >> 1) & 3);
      bfr[nt] = *(const short8*)&Bs[R * BK + slot * 8];
    }
    #pragma unroll
    for (int mt = 0; mt < 4; ++mt)
      #pragma unroll
      for (int nt = 0; nt < 4; ++nt)
        acc[mt][nt] = __builtin_amdgcn_mfma_f32_16x16x32_bf16(
            af[mt], bfr[nt], acc[mt][nt], 0, 0, 0);
    __syncthreads();
  }

  // ---- epilogue.  D layout: col = lane&15, row = quad*4 + reg ----
  #pragma unroll
  for (int mt = 0; mt < 4; ++mt) {
    #pragma unroll
    for (int nt = 0; nt < 4; ++nt) {
      #pragma unroll
      for (int r = 0; r < 4; ++r) {
        const int Rg = m0 + wm + mt * 16 + quad * 4 + r;
        const int Cg = n0 + wn + nt * 16 + l16;
        const size_t off = (size_t)z * (size_t)sC + (size_t)Rg * ldc + Cg;
        const float val = acc[mt][nt][r];
        if (EPI == 0) {
          ((unsigned short*)Cbase)[off] = f2bf(val + bias[Cg]);
        } else if (EPI == 1) {
          ((unsigned short*)Cbase)[off] = f2h(val * scale);
        } else {
          ((float*)Cbase)[off] = val * scale;
        }
      }
    }
  }
}

// ---------------------------------------------------------------------------
// fp32 -> bf16 elementwise for the three [8,2048,1024] inputs (z selects).
// ---------------------------------------------------------------------------
__global__ __launch_bounds__(256) void cvt3_bf16(
    const float* __restrict__ a, const float* __restrict__ b,
    const float* __restrict__ c,
    unsigned short* __restrict__ oa, unsigned short* __restrict__ ob,
    unsigned short* __restrict__ oc)
{
  const float* src = blockIdx.z == 0 ? a : (blockIdx.z == 1 ? b : c);
  unsigned short* dst = blockIdx.z == 0 ? oa : (blockIdx.z == 1 ? ob : oc);
  const size_t base = ((size_t)blockIdx.x * 256 + threadIdx.x) * 8;
  const float4 t0 = *(const float4*)(src + base);
  const float4 t1 = *(const float4*)(src + base + 4);
  ushort8v h;
  h[0] = f2bf(t0.x); h[1] = f2bf(t0.y); h[2] = f2bf(t0.z); h[3] = f2bf(t0.w);
  h[4] = f2bf(t1.x); h[5] = f2bf(t1.y); h[6] = f2bf(t1.z); h[7] = f2bf(t1.w);
  *(ushort8v*)(dst + base) = h;
}

// ---------------------------------------------------------------------------
// Wq [1024x1024] fp32 -> Wt [1024x1024] bf16 transposed
// ---------------------------------------------------------------------------
__global__ __launch_bounds__(256) void transpose_w(
    const float* __restrict__ W, unsigned short* __restrict__ Wt)
{
  __shared__ float tile[64][65];
  const int k0 = blockIdx.x * 64;
  const int n0 = blockIdx.y * 64;
  #pragma unroll
  for (int i = 0; i < 16; ++i) {
    int lin = threadIdx.x + i * 256;
    int r = lin >> 6, c = lin & 63;
    tile[r][c] = W[(size_t)(k0 + r) * 1024 + n0 + c];
  }
  __syncthreads();
  #pragma unroll
  for (int i = 0; i < 16; ++i) {
    int lin = threadIdx.x + i * 256;
    int r = lin >> 6, c = lin & 63;
    Wt[(size_t)(n0 + r) * 1024 + k0 + c] = f2bf(tile[c][r]);
  }
}

// ---------------------------------------------------------------------------
// v [b][2048][1024] bf16 -> vT [b][1024][2048] bf16
// ---------------------------------------------------------------------------
__global__ __launch_bounds__(256) void transpose_v(
    const unsigned short* __restrict__ V, unsigned short* __restrict__ VT)
{
  __shared__ unsigned short tile[64][66];
  const int b  = blockIdx.z;
  const int s0 = blockIdx.x * 64;
  const int d0 = blockIdx.y * 64;
  const unsigned short* Vb  = V  + (size_t)b * 2048 * 1024;
  unsigned short*       VTb = VT + (size_t)b * 1024 * 2048;
  #pragma unroll
  for (int i = 0; i < 16; ++i) {
    int lin = threadIdx.x + i * 256;
    int r = lin >> 6, c = lin & 63;
    tile[r][c] = Vb[(size_t)(s0 + r) * 1024 + d0 + c];
  }
  __syncthreads();
  #pragma unroll
  for (int i = 0; i < 16; ++i) {
    int lin = threadIdx.x + i * 256;
    int r = lin >> 6, c = lin & 63;
    VTb[(size_t)(d0 + r) * 2048 + s0 + c] = tile[c][r];
  }
}

// ---------------------------------------------------------------------------
// Row softmax: read fp16 logits row (2048), write bf16 P row (2048).
// One block per row; each thread owns 8 contiguous elements (one 16B chunk).
// ---------------------------------------------------------------------------
__global__ __launch_bounds__(256) void softmax_rows(
    const unsigned short* __restrict__ Lh, unsigned short* __restrict__ P)
{
  const int row  = blockIdx.x;
  const unsigned short* pin = Lh + (size_t)row * 2048;
  unsigned short*       pout = P + (size_t)row * 2048;
  const int tid  = threadIdx.x;
  const int lane = tid & 63;
  const int wave = tid >> 6;

  const ushort8v h = ((const ushort8v*)pin)[tid];
  float x[8];
  #pragma unroll
  for (int e = 0; e < 8; ++e) x[e] = h2f(h[e]);

  float mx = x[0];
  #pragma unroll
  for (int e = 1; e < 8; ++e) mx = fmaxf(mx, x[e]);
  #pragma unroll
  for (int o = 32; o > 0; o >>= 1) mx = fmaxf(mx, __shfl_xor(mx, o));
  __shared__ float redm[4];
  if (lane == 0) redm[wave] = mx;
  __syncthreads();
  mx = fmaxf(fmaxf(redm[0], redm[1]), fmaxf(redm[2], redm[3]));

  float s = 0.f;
  #pragma unroll
  for (int e = 0; e < 8; ++e) { x[e] = __expf(x[e] - mx); s += x[e]; }
  #pragma unroll
  for (int o = 32; o > 0; o >>= 1) s += __shfl_xor(s, o);
  __shared__ float reds[4];
  if (lane == 0) reds[wave] = s;
  __syncthreads();
  s = reds[0] + reds[1] + reds[2] + reds[3];

  const float inv = 1.0f / s;
  ushort8v o8;
  #pragma unroll
  for (int e = 0; e < 8; ++e) o8[e] = f2bf(x[e] * inv);
  ((ushort8v*)pout)[tid] = o8;
}

// ---------------------------------------------------------------------------
extern "C" void kernel_launch(void* const* d_in, const int* in_sizes, int n_in,
                              void* d_out, int out_size, void* d_ws, size_t ws_size,
                              hipStream_t stream)
{
  const float* query = (const float*)d_in[0];
  const float* key   = (const float*)d_in[1];
  const float* value = (const float*)d_in[2];
  const float* Wq    = (const float*)d_in[3];
  const float* bq    = (const float*)d_in[4];
  float* out = (float*)d_out;

  // workspace (MB offsets), peak 226 MB:
  //   Wt  [0,2)     bf16 W^T
  //   Xq  [2,34) Xk [34,66) Xv [66,98)    bf16 converted inputs
  //   q   [98,130) k [130,162) v [162,194) bf16 projections
  //   vT  [2,34)    over dead Xq (after q-proj)
  //   lgH [34,98)   fp16 logits, over dead Xk/Xv (after projections)
  //   P   [98,162)  bf16 probs, over dead q/k (after QK^T)
  char* ws = (char*)d_ws;
  unsigned short* Wt  = (unsigned short*)(ws);
  unsigned short* Xq  = (unsigned short*)(ws + ((size_t)2   << 20));
  unsigned short* Xk  = (unsigned short*)(ws + ((size_t)34  << 20));
  unsigned short* Xv  = (unsigned short*)(ws + ((size_t)66  << 20));
  unsigned short* q   = (unsigned short*)(ws + ((size_t)98  << 20));
  unsigned short* k   = (unsigned short*)(ws + ((size_t)130 << 20));
  unsigned short* v   = (unsigned short*)(ws + ((size_t)162 << 20));
  unsigned short* vT  = (unsigned short*)(ws + ((size_t)2   << 20));
  unsigned short* lgH = (unsigned short*)(ws + ((size_t)34  << 20));
  unsigned short* P   = (unsigned short*)(ws + ((size_t)98  << 20));

  // 1. W transpose->bf16 ; inputs fp32->bf16
  transpose_w<<<dim3(16, 16, 1), 256, 0, stream>>>(Wq, Wt);
  cvt3_bf16<<<dim3(8192, 1, 3), 256, 0, stream>>>(query, key, value, Xq, Xk, Xv);

  // 2. projections: bf16 = X @ Wt^T + bq   (M=16384, N=1024, K=1024)
  dim3 gproj(16384 / BM, 1024 / BN, 1);
  gemm_bf16<0><<<gproj, 256, 0, stream>>>(Xq, Wt, q, bq, 1.0f,
      1024, 1024, 1024, 1024, 0, 0, 0);
  gemm_bf16<0><<<gproj, 256, 0, stream>>>(Xk, Wt, k, bq, 1.0f,
      1024, 1024, 1024, 1024, 0, 0, 0);
  gemm_bf16<0><<<gproj, 256, 0, stream>>>(Xv, Wt, v, bq, 1.0f,
      1024, 1024, 1024, 1024, 0, 0, 0);

  // 3. v -> vT  (writes over dead Xq)
  transpose_v<<<dim3(32, 16, 8), 256, 0, stream>>>(v, vT);

  // 4. logits[fp16] = (q @ k^T)/32  per batch (M=N=2048, K=1024)
  gemm_bf16<1><<<dim3(16, 16, 8), 256, 0, stream>>>(q, k, lgH, nullptr,
      0.03125f, 1024, 1024, 2048, 1024,
      (long long)2048 * 1024, (long long)2048 * 1024, (long long)2048 * 2048);

  // 5. softmax rows -> bf16 P (writes over dead q/k)
  softmax_rows<<<dim3(8 * 2048, 1, 1), 256, 0, stream>>>(lgH, P);

  // 6. out[f32] = P @ vT^T  per batch (M=2048, N=1024, K=2048)
  gemm_bf16<2><<<dim3(16, 8, 8), 256, 0, stream>>>(P, vT, out, nullptr, 1.0f,
      2048, 2048, 1024, 2048,
      (long long)2048 * 2048, (long long)1024 * 2048, (long long)2048 * 1024);
}

// Round 3
// 556.189 us; speedup vs baseline: 1.3339x; 1.1152x over previous
//
#include <hip/hip_runtime.h>
#include <hip/hip_bf16.h>
#include <stdint.h>

typedef __attribute__((ext_vector_type(8))) short short8;
typedef __attribute__((ext_vector_type(4))) float f32x4;
typedef __attribute__((ext_vector_type(8))) unsigned short ushort8v;

__device__ __forceinline__ unsigned short f2bf(float f) {
  union { float f; uint32_t u; } v; v.f = f;
  uint32_t u = v.u;
  u += 0x7fffu + ((u >> 16) & 1u);   // round-to-nearest-even
  return (unsigned short)(u >> 16);
}
__device__ __forceinline__ unsigned short f2h(float f) {
  union { _Float16 h; unsigned short u; } v; v.h = (_Float16)f; return v.u;
}
__device__ __forceinline__ float h2f(unsigned short u) {
  union { _Float16 h; unsigned short u; } v; v.u = u; return (float)v.h;
}

typedef const __attribute__((address_space(1))) unsigned int* gas_ptr;
typedef __attribute__((address_space(3))) unsigned int* las_ptr;

// DMA 16B per lane: LDS dst = wave-uniform base + lane*16 (hardware rule)
__device__ __forceinline__ void async16(const unsigned short* g, unsigned short* l) {
  __builtin_amdgcn_global_load_lds((gas_ptr)g, (las_ptr)l, 16, 0, 0);
}

// ---------------------------------------------------------------------------
// C = A * B^T, all-bf16.  A:[M,K], B:[N,K] row-major bf16.
// BM=BN=128, BK=64 (one barrier-pair per K=64 -> half the vmcnt drains of
// BK=32).  256 threads = 4 waves, wave = 64x64 quadrant as 4x4 grid of
// 16x16x32 bf16 MFMAs x 2 K-halves.  LDS 2x16KB, chunk-swizzled:
// 16B chunk j of row r stored at slot j ^ (r&7) -> fragment reads are 2-way
// on banks per quad phase (free).
// EPI 0: bf16 = val + bias[col]; EPI 1: fp16 = val*scale; EPI 2: f32 = val*scale
// ---------------------------------------------------------------------------
#define BM 128
#define BN 128
#define BK 64

template<int EPI>
__global__ __launch_bounds__(256) void gemm_bf16(
    const unsigned short* __restrict__ Abase,
    const unsigned short* __restrict__ Bbase,
    void* __restrict__ Cbase, const float* __restrict__ bias, float scale,
    int lda, int ldb, int ldc, int K,
    long long sA, long long sB, long long sC)
{
  __shared__ __align__(16) unsigned short As[BM * BK];  // 16 KB
  __shared__ __align__(16) unsigned short Bs[BN * BK];  // 16 KB

  const int tid  = threadIdx.x;
  const int z    = blockIdx.z;
  const int m0   = blockIdx.x * BM;
  const int n0   = blockIdx.y * BN;
  const int wave = tid >> 6;
  const int lane = tid & 63;
  const int l16  = lane & 15;
  const int quad = lane >> 4;
  const int wm   = (wave >> 1) * 64;
  const int wn   = (wave & 1) * 64;

  const unsigned short* A = Abase + (size_t)z * (size_t)sA;
  const unsigned short* B = Bbase + (size_t)z * (size_t)sB;

  f32x4 acc[4][4] = {};

  const int nk = K / BK;
  for (int kt = 0; kt < nk; ++kt) {
    const int k0 = kt * BK;
    // ---- DMA stage A and B tiles (each 128x64 bf16 = 16 KB, 1024 chunks) ----
    #pragma unroll
    for (int j = 0; j < 4; ++j) {
      const int i  = j * 256 + tid;       // linear 16B-chunk index [0,1024)
      const int r  = i >> 3;              // row in tile
      const int s  = i & 7;               // LDS slot within row
      const int jc = s ^ (r & 7);         // global chunk to fetch (swizzle)
      unsigned short* ldst_a = As + (size_t)(j * 256 + wave * 64) * 8; // uniform
      unsigned short* ldst_b = Bs + (size_t)(j * 256 + wave * 64) * 8;
      async16(A + (size_t)(m0 + r) * lda + k0 + jc * 8, ldst_a);
      async16(B + (size_t)(n0 + r) * ldb + k0 + jc * 8, ldst_b);
    }
    __syncthreads();

    // ---- two K-halves of 16x16x32 MFMAs ----
    #pragma unroll
    for (int h = 0; h < 2; ++h) {
      short8 af[4], bfr[4];
      #pragma unroll
      for (int mt = 0; mt < 4; ++mt) {
        const int R = wm + mt * 16 + l16;
        const int slot = (h * 4 + quad) ^ (R & 7);
        af[mt] = *(const short8*)&As[R * BK + slot * 8];
      }
      #pragma unroll
      for (int nt = 0; nt < 4; ++nt) {
        const int R = wn + nt * 16 + l16;
        const int slot = (h * 4 + quad) ^ (R & 7);
        bfr[nt] = *(const short8*)&Bs[R * BK + slot * 8];
      }
      #pragma unroll
      for (int mt = 0; mt < 4; ++mt)
        #pragma unroll
        for (int nt = 0; nt < 4; ++nt)
          acc[mt][nt] = __builtin_amdgcn_mfma_f32_16x16x32_bf16(
              af[mt], bfr[nt], acc[mt][nt], 0, 0, 0);
    }
    __syncthreads();
  }

  // ---- epilogue.  D layout: col = lane&15, row = quad*4 + reg ----
  #pragma unroll
  for (int mt = 0; mt < 4; ++mt) {
    #pragma unroll
    for (int nt = 0; nt < 4; ++nt) {
      #pragma unroll
      for (int r = 0; r < 4; ++r) {
        const int Rg = m0 + wm + mt * 16 + quad * 4 + r;
        const int Cg = n0 + wn + nt * 16 + l16;
        const size_t off = (size_t)z * (size_t)sC + (size_t)Rg * ldc + Cg;
        const float val = acc[mt][nt][r];
        if (EPI == 0) {
          ((unsigned short*)Cbase)[off] = f2bf(val + bias[Cg]);
        } else if (EPI == 1) {
          ((unsigned short*)Cbase)[off] = f2h(val * scale);
        } else {
          ((float*)Cbase)[off] = val * scale;
        }
      }
    }
  }
}

// ---------------------------------------------------------------------------
// fp32 -> bf16 elementwise for the three [8,2048,1024] inputs (z selects).
// ---------------------------------------------------------------------------
__global__ __launch_bounds__(256) void cvt3_bf16(
    const float* __restrict__ a, const float* __restrict__ b,
    const float* __restrict__ c,
    unsigned short* __restrict__ oa, unsigned short* __restrict__ ob,
    unsigned short* __restrict__ oc)
{
  const float* src = blockIdx.z == 0 ? a : (blockIdx.z == 1 ? b : c);
  unsigned short* dst = blockIdx.z == 0 ? oa : (blockIdx.z == 1 ? ob : oc);
  const size_t base = ((size_t)blockIdx.x * 256 + threadIdx.x) * 8;
  const float4 t0 = *(const float4*)(src + base);
  const float4 t1 = *(const float4*)(src + base + 4);
  ushort8v h;
  h[0] = f2bf(t0.x); h[1] = f2bf(t0.y); h[2] = f2bf(t0.z); h[3] = f2bf(t0.w);
  h[4] = f2bf(t1.x); h[5] = f2bf(t1.y); h[6] = f2bf(t1.z); h[7] = f2bf(t1.w);
  *(ushort8v*)(dst + base) = h;
}

// ---------------------------------------------------------------------------
// Wq [1024x1024] fp32 -> Wt [1024x1024] bf16 transposed
// ---------------------------------------------------------------------------
__global__ __launch_bounds__(256) void transpose_w(
    const float* __restrict__ W, unsigned short* __restrict__ Wt)
{
  __shared__ float tile[64][65];
  const int k0 = blockIdx.x * 64;
  const int n0 = blockIdx.y * 64;
  #pragma unroll
  for (int i = 0; i < 16; ++i) {
    int lin = threadIdx.x + i * 256;
    int r = lin >> 6, c = lin & 63;
    tile[r][c] = W[(size_t)(k0 + r) * 1024 + n0 + c];
  }
  __syncthreads();
  #pragma unroll
  for (int i = 0; i < 16; ++i) {
    int lin = threadIdx.x + i * 256;
    int r = lin >> 6, c = lin & 63;
    Wt[(size_t)(n0 + r) * 1024 + k0 + c] = f2bf(tile[c][r]);
  }
}

// ---------------------------------------------------------------------------
// v [b][2048][1024] bf16 -> vT [b][1024][2048] bf16
// ---------------------------------------------------------------------------
__global__ __launch_bounds__(256) void transpose_v(
    const unsigned short* __restrict__ V, unsigned short* __restrict__ VT)
{
  __shared__ unsigned short tile[64][66];
  const int b  = blockIdx.z;
  const int s0 = blockIdx.x * 64;
  const int d0 = blockIdx.y * 64;
  const unsigned short* Vb  = V  + (size_t)b * 2048 * 1024;
  unsigned short*       VTb = VT + (size_t)b * 1024 * 2048;
  #pragma unroll
  for (int i = 0; i < 16; ++i) {
    int lin = threadIdx.x + i * 256;
    int r = lin >> 6, c = lin & 63;
    tile[r][c] = Vb[(size_t)(s0 + r) * 1024 + d0 + c];
  }
  __syncthreads();
  #pragma unroll
  for (int i = 0; i < 16; ++i) {
    int lin = threadIdx.x + i * 256;
    int r = lin >> 6, c = lin & 63;
    VTb[(size_t)(d0 + r) * 2048 + s0 + c] = tile[c][r];
  }
}

// ---------------------------------------------------------------------------
// Row softmax: read fp16 logits row (2048), write bf16 P row (2048).
// ---------------------------------------------------------------------------
__global__ __launch_bounds__(256) void softmax_rows(
    const unsigned short* __restrict__ Lh, unsigned short* __restrict__ P)
{
  const int row  = blockIdx.x;
  const unsigned short* pin = Lh + (size_t)row * 2048;
  unsigned short*       pout = P + (size_t)row * 2048;
  const int tid  = threadIdx.x;
  const int lane = tid & 63;
  const int wave = tid >> 6;

  const ushort8v h = ((const ushort8v*)pin)[tid];
  float x[8];
  #pragma unroll
  for (int e = 0; e < 8; ++e) x[e] = h2f(h[e]);

  float mx = x[0];
  #pragma unroll
  for (int e = 1; e < 8; ++e) mx = fmaxf(mx, x[e]);
  #pragma unroll
  for (int o = 32; o > 0; o >>= 1) mx = fmaxf(mx, __shfl_xor(mx, o));
  __shared__ float redm[4];
  if (lane == 0) redm[wave] = mx;
  __syncthreads();
  mx = fmaxf(fmaxf(redm[0], redm[1]), fmaxf(redm[2], redm[3]));

  float s = 0.f;
  #pragma unroll
  for (int e = 0; e < 8; ++e) { x[e] = __expf(x[e] - mx); s += x[e]; }
  #pragma unroll
  for (int o = 32; o > 0; o >>= 1) s += __shfl_xor(s, o);
  __shared__ float reds[4];
  if (lane == 0) reds[wave] = s;
  __syncthreads();
  s = reds[0] + reds[1] + reds[2] + reds[3];

  const float inv = 1.0f / s;
  ushort8v o8;
  #pragma unroll
  for (int e = 0; e < 8; ++e) o8[e] = f2bf(x[e] * inv);
  ((ushort8v*)pout)[tid] = o8;
}

// ---------------------------------------------------------------------------
extern "C" void kernel_launch(void* const* d_in, const int* in_sizes, int n_in,
                              void* d_out, int out_size, void* d_ws, size_t ws_size,
                              hipStream_t stream)
{
  const float* query = (const float*)d_in[0];
  const float* key   = (const float*)d_in[1];
  const float* value = (const float*)d_in[2];
  const float* Wq    = (const float*)d_in[3];
  const float* bq    = (const float*)d_in[4];
  float* out = (float*)d_out;

  // workspace (MB offsets), peak 226 MB:
  //   Wt  [0,2)     bf16 W^T
  //   Xq  [2,34) Xk [34,66) Xv [66,98)    bf16 inputs (contiguous -> one GEMM)
  //   q   [98,130) k [130,162) v [162,194) bf16 projections (contiguous)
  //   vT  [2,34)    over dead Xq
  //   lgH [34,98)   fp16 logits over dead Xk/Xv
  //   P   [98,162)  bf16 probs over dead q/k
  char* ws = (char*)d_ws;
  unsigned short* Wt  = (unsigned short*)(ws);
  unsigned short* Xq  = (unsigned short*)(ws + ((size_t)2   << 20));
  unsigned short* Xk  = (unsigned short*)(ws + ((size_t)34  << 20));
  unsigned short* Xv  = (unsigned short*)(ws + ((size_t)66  << 20));
  unsigned short* q   = (unsigned short*)(ws + ((size_t)98  << 20));
  unsigned short* v   = (unsigned short*)(ws + ((size_t)162 << 20));
  unsigned short* vT  = (unsigned short*)(ws + ((size_t)2   << 20));
  unsigned short* lgH = (unsigned short*)(ws + ((size_t)34  << 20));
  unsigned short* P   = (unsigned short*)(ws + ((size_t)98  << 20));

  // 1. W transpose->bf16 ; inputs fp32->bf16
  transpose_w<<<dim3(16, 16, 1), 256, 0, stream>>>(Wq, Wt);
  cvt3_bf16<<<dim3(8192, 1, 3), 256, 0, stream>>>(query, key, value, Xq, Xk, Xv);

  // 2. projections (single dispatch, z=0,1,2 over contiguous X/q-k-v):
  //    bf16 = X @ Wt^T + bq   (M=16384, N=1024, K=1024)
  gemm_bf16<0><<<dim3(16384 / BM, 1024 / BN, 3), 256, 0, stream>>>(
      Xq, Wt, q, bq, 1.0f, 1024, 1024, 1024, 1024,
      (long long)16384 * 1024, 0, (long long)16384 * 1024);

  // 3. v -> vT  (writes over dead Xq)
  transpose_v<<<dim3(32, 16, 8), 256, 0, stream>>>(v, vT);

  // 4. logits[fp16] = (q @ k^T)/32  per batch (M=N=2048, K=1024)
  gemm_bf16<1><<<dim3(16, 16, 8), 256, 0, stream>>>(q, q + (size_t)32 * 1024 * 1024 / 2,
      lgH, nullptr, 0.03125f, 1024, 1024, 2048, 1024,
      (long long)2048 * 1024, (long long)2048 * 1024, (long long)2048 * 2048);

  // 5. softmax rows -> bf16 P (writes over dead q/k)
  softmax_rows<<<dim3(8 * 2048, 1, 1), 256, 0, stream>>>(lgH, P);

  // 6. out[f32] = P @ vT^T  per batch (M=2048, N=1024, K=2048)
  gemm_bf16<2><<<dim3(16, 8, 8), 256, 0, stream>>>(P, vT, out, nullptr, 1.0f,
      2048, 2048, 1024, 2048,
      (long long)2048 * 2048, (long long)1024 * 2048, (long long)2048 * 1024);
}